// Round 8
// baseline (394.328 us; speedup 1.0000x reference)
//
#include <hip/hip_runtime.h>
#include <hip/hip_bf16.h>
#include <math.h>

// Bahdanau attention + reservoir RNN cell.
//  K0: Ua_w f32 -> bf16 in MFMA B-fragment layout (L2-resident, read direct)
//  K1: q = h_prev@Wa^T + Wa_b + Ua_b
//  K2: per (b, 64-row chunk): 512 threads / 8 waves, acc 4x4/wave.
//      A in LDS stored FRAGMENT-MAJOR: tile (mt,kt) = 1KB, lane-contiguous.
//      ds_read_b128 at vaddr=l*16 + immediate t*1024 -> conflict-free reads,
//      no addressing VALU. (Old row-major XOR layout was 8-way bank-conflicted:
//      row*1024 == 0 mod 128B, bank set = P%8 only -> SQ_LDS_BANK_CONFLICT
//      clipped at 2^23 every dispatch, R3-R7.)
//      B: fragment-layout from L2 with depth-2 register pipeline (b0/b1/b2).
//      Epilogue: tanh(q+k)·Va -> partial softmax; partial context re-reads the
//      f32 tile from global (L2-warm) — fragment-major LDS is bank-hostile
//      along k, so no LDS context pass.
//  K3: exact combine of 32 partials -> context
//  K4: RNN cell (grid split over o for full-chip coverage)

typedef __attribute__((ext_vector_type(8))) short short8;
typedef __attribute__((ext_vector_type(8))) unsigned short ushort8;
typedef __attribute__((ext_vector_type(4))) float f32x4;

#define S_LEN 2048
#define BDIM 128
#define HDIM 512
#define EDIM 512
#define BM 64
#define BK 128
#define NK (HDIM / BK)       // 4
#define NCHUNK (S_LEN / BM)  // 32

__device__ __forceinline__ unsigned short f2bf(float f) {
  unsigned int u = __float_as_uint(f);
  u += 0x7fffu + ((u >> 16) & 1u);  // RNE
  return (unsigned short)(u >> 16);
}

__device__ __forceinline__ float fast_tanh(float x) {
  float e = __expf(2.0f * x);
  return 1.0f - 2.0f / (e + 1.0f);
}

// Ua[512][512] f32 -> bf16 fragment layout:
// tile (ct,kt): col = ct*16 + (l&15), k = kt*32 + (l>>4)*8 + e
// at dst[((ct*16+kt)*64 + l)*8 + e]
__global__ __launch_bounds__(256) void k_cvt_b(const float* __restrict__ src,
                                               unsigned short* __restrict__ dst) {
  int tid = blockIdx.x * 256 + threadIdx.x;  // 0..32767
  int ct = tid >> 10;
  int kt = (tid >> 6) & 15;
  int l = tid & 63;
  int col = ct * 16 + (l & 15);
  int k = kt * 32 + (l >> 4) * 8;
  const float4* s = (const float4*)(src + (size_t)col * HDIM + k);
  float4 v0 = s[0], v1 = s[1];
  ushort8 p;
  p[0] = f2bf(v0.x); p[1] = f2bf(v0.y); p[2] = f2bf(v0.z); p[3] = f2bf(v0.w);
  p[4] = f2bf(v1.x); p[5] = f2bf(v1.y); p[6] = f2bf(v1.z); p[7] = f2bf(v1.w);
  *(ushort8*)(dst + (size_t)tid * 8) = p;
}

__global__ __launch_bounds__(256) void k_q(const float* __restrict__ hp,
                                           const float* __restrict__ Wa,
                                           const float* __restrict__ Wab,
                                           const float* __restrict__ Uab,
                                           float* __restrict__ q) {
  int b = blockIdx.x, oh = blockIdx.y;
  int o = oh * 256 + threadIdx.x;
  __shared__ float hs[HDIM];
  hs[threadIdx.x] = hp[b * HDIM + threadIdx.x];
  hs[threadIdx.x + 256] = hp[b * HDIM + threadIdx.x + 256];
  __syncthreads();
  const float4* wr = (const float4*)(Wa + (size_t)o * HDIM);
  float acc = 0.f;
#pragma unroll 8
  for (int i = 0; i < HDIM / 4; ++i) {
    float4 v = wr[i];
    acc += v.x * hs[i * 4 + 0] + v.y * hs[i * 4 + 1] + v.z * hs[i * 4 + 2] + v.w * hs[i * 4 + 3];
  }
  q[b * HDIM + o] = acc + Wab[o] + Uab[o];
}

__global__ __launch_bounds__(512) void k_scores_ctx(
    const float* __restrict__ xref, const unsigned short* __restrict__ uab,
    const float* __restrict__ q, const float* __restrict__ va,
    float* __restrict__ mArr, float* __restrict__ lArr, float* __restrict__ cpart) {
  int chunk = blockIdx.x;
  int b = blockIdx.y;
  int tid = threadIdx.x;
  int l = tid & 63;
  int w = tid >> 6;   // 0..7, wave owns 64 output cols

  // Fragment-major A: tile t = mt*16 + kt (mt=row>>4, kt=k>>5), 512 ushorts per
  // tile; slot l holds row=(mt*16+(l&15)), k = kt*32 + (l>>4)*8 .. +7.
  __shared__ __align__(16) unsigned short As[BM * HDIM];  // 64 KB
  __shared__ float sc[BM];
  __shared__ float pl[BM];
  if (tid < BM) sc[tid] = 0.f;

  f32x4 acc[4][4];
#pragma unroll
  for (int m = 0; m < 4; ++m)
#pragma unroll
    for (int n = 0; n < 4; ++n) acc[m][n] = f32x4{0.f, 0.f, 0.f, 0.f};

  const float* xb = xref + ((size_t)b * S_LEN + (size_t)chunk * BM) * HDIM;

  // staging: 8 threads per row; thread covers 16 consecutive floats at
  // k = kc*128 + skq*16 -> two slots of tile (srow>>4)*16 + kc*4 + (skq>>1)
  int srow = tid >> 3, skq = tid & 7;
  const float* sbase = xb + (size_t)srow * HDIM + (size_t)skq * 16;
  // ushort-unit base of first write (kc=0): tile*512 + slot*8
  int a0 = ((srow >> 4) * 16 + (skq >> 1)) * 512 + ((srow & 15) + 32 * (skq & 1)) * 8;

  float4 xa0, xa1, xb0, xb1;
  short8 b0[4], b1[4], b2[4];

#define LOADKC(kc)                                      \
  {                                                     \
    const float* bp = sbase + (kc) * BK;                \
    xa0 = ((const float4*)bp)[0];                       \
    xa1 = ((const float4*)bp)[1];                       \
    xb0 = ((const float4*)bp)[2];                       \
    xb1 = ((const float4*)bp)[3];                       \
  }

#define WRITEKC(kc)                                                    \
  {                                                                    \
    ushort8 pA, pB;                                                    \
    pA[0] = f2bf(xa0.x); pA[1] = f2bf(xa0.y); pA[2] = f2bf(xa0.z);     \
    pA[3] = f2bf(xa0.w); pA[4] = f2bf(xa1.x); pA[5] = f2bf(xa1.y);     \
    pA[6] = f2bf(xa1.z); pA[7] = f2bf(xa1.w);                          \
    pB[0] = f2bf(xb0.x); pB[1] = f2bf(xb0.y); pB[2] = f2bf(xb0.z);     \
    pB[3] = f2bf(xb0.w); pB[4] = f2bf(xb1.x); pB[5] = f2bf(xb1.y);     \
    pB[6] = f2bf(xb1.z); pB[7] = f2bf(xb1.w);                          \
    *(ushort8*)&As[a0 + (kc) * 2048] = pA;                             \
    *(ushort8*)&As[a0 + (kc) * 2048 + 128] = pB;                       \
  }

  // load B fragments for k-tile kt into statically-named register buffer
#define LOADB(dst, kt)                                                        \
  {                                                                           \
    _Pragma("unroll")                                                         \
    for (int n = 0; n < 4; ++n)                                               \
      dst[n] = *(const short8*)(uab +                                         \
               (((size_t)((w * 4 + n) * 16 + (kt)) * 64 + l) * 8));           \
  }

  // 16-MFMA cluster on (kc,kk): A reads lane-contiguous, imm offset = t*1KB
#define CLUSTER(breg, kc, kk)                                                 \
  {                                                                           \
    short8 afr[4];                                                            \
    _Pragma("unroll")                                                         \
    for (int m = 0; m < 4; ++m)                                               \
      afr[m] = *(const short8*)&As[((m * 16 + (kc) * 4 + (kk)) << 9) + (l << 3)]; \
    __builtin_amdgcn_s_setprio(1);                                            \
    _Pragma("unroll")                                                         \
    for (int m = 0; m < 4; ++m)                                               \
      _Pragma("unroll")                                                       \
      for (int n = 0; n < 4; ++n)                                             \
        acc[m][n] = __builtin_amdgcn_mfma_f32_16x16x32_bf16(afr[m], breg[n],  \
                                                            acc[m][n], 0, 0, 0); \
    __builtin_amdgcn_s_setprio(0);                                            \
  }

  LOADKC(0);
  WRITEKC(0);
  LOADB(b0, 0);
  LOADB(b1, 1);
  __syncthreads();

  // phase 0: kc=0, kt 0..3
  LOADKC(1);
  LOADB(b2, 2);  CLUSTER(b0, 0, 0);
  LOADB(b0, 3);  CLUSTER(b1, 0, 1);
  LOADB(b1, 4);  CLUSTER(b2, 0, 2);
  LOADB(b2, 5);  CLUSTER(b0, 0, 3);
  WRITEKC(1);
  __syncthreads();

  // phase 1: kc=1, kt 4..7
  LOADKC(2);
  LOADB(b0, 6);  CLUSTER(b1, 1, 0);
  LOADB(b1, 7);  CLUSTER(b2, 1, 1);
  LOADB(b2, 8);  CLUSTER(b0, 1, 2);
  LOADB(b0, 9);  CLUSTER(b1, 1, 3);
  WRITEKC(2);
  __syncthreads();

  // phase 2: kc=2, kt 8..11
  LOADKC(3);
  LOADB(b1, 10); CLUSTER(b2, 2, 0);
  LOADB(b2, 11); CLUSTER(b0, 2, 1);
  LOADB(b0, 12); CLUSTER(b1, 2, 2);
  LOADB(b1, 13); CLUSTER(b2, 2, 3);
  WRITEKC(3);
  __syncthreads();

  // phase 3: kc=3, kt 12..15; q/Va loads hoisted under the first clusters
  int c = l & 15, g4 = l >> 4;
  float qf[4], vf[4];
#pragma unroll
  for (int n = 0; n < 4; ++n) {
    int o = w * 64 + n * 16 + c;
    qf[n] = q[b * HDIM + o];
    vf[n] = va[o];
  }
  LOADB(b2, 14); CLUSTER(b0, 3, 0);
  LOADB(b0, 15); CLUSTER(b1, 3, 1);
                 CLUSTER(b2, 3, 2);
                 CLUSTER(b0, 3, 3);

  // scores[row] = sum_o tanh(acc + q[o]) * Va[o]
#pragma unroll
  for (int m = 0; m < 4; ++m) {
#pragma unroll
    for (int r = 0; r < 4; ++r) {
      float sum = 0.f;
#pragma unroll
      for (int n = 0; n < 4; ++n) sum += fast_tanh(acc[m][n][r] + qf[n]) * vf[n];
      sum += __shfl_xor(sum, 1);
      sum += __shfl_xor(sum, 2);
      sum += __shfl_xor(sum, 4);
      sum += __shfl_xor(sum, 8);
      if (c == 0) atomicAdd(&sc[m * 16 + g4 * 4 + r], sum);
    }
  }
  __syncthreads();

  // partial softmax over the 64 local rows
  float M = sc[l];
#pragma unroll
  for (int off = 32; off >= 1; off >>= 1) M = fmaxf(M, __shfl_xor(M, off));
  float p = __expf(sc[l] - M);
  float lsum = p;
#pragma unroll
  for (int off = 32; off >= 1; off >>= 1) lsum += __shfl_xor(lsum, off);
  if (tid < BM) pl[tid] = p;
  if (tid == 0) {
    mArr[b * NCHUNK + chunk] = M;
    lArr[b * NCHUNK + chunk] = lsum;
  }
  __syncthreads();

  // partial context: re-read the f32 tile from global (L2-warm; coalesced
  // 256B/wave per row). Fragment-major LDS can't serve along-k reads.
  {
    float cacc = 0.f;
#pragma unroll 8
    for (int r = 0; r < BM; ++r) cacc += pl[r] * xb[(size_t)r * HDIM + tid];
    cpart[((size_t)b * NCHUNK + chunk) * HDIM + tid] = cacc;
  }
#undef LOADKC
#undef WRITEKC
#undef LOADB
#undef CLUSTER
}

__global__ __launch_bounds__(512) void k_combine(const float* __restrict__ mArr,
                                                 const float* __restrict__ lArr,
                                                 const float* __restrict__ cpart,
                                                 float* __restrict__ ctx,
                                                 float* __restrict__ out_ctx) {
  int b = blockIdx.x, t = threadIdx.x;
  __shared__ float wf[NCHUNK];
  __shared__ float dinv;
  if (t == 0) {
    float M = mArr[b * NCHUNK];
    for (int i = 1; i < NCHUNK; ++i) M = fmaxf(M, mArr[b * NCHUNK + i]);
    float den = 0.f;
    for (int i = 0; i < NCHUNK; ++i) {
      float f = __expf(mArr[b * NCHUNK + i] - M);
      wf[i] = f;
      den += f * lArr[b * NCHUNK + i];
    }
    dinv = 1.0f / den;
  }
  __syncthreads();
  float s = 0.f;
#pragma unroll
  for (int i = 0; i < NCHUNK; ++i) s += wf[i] * cpart[((size_t)b * NCHUNK + i) * HDIM + t];
  float c = s * dinv;
  ctx[b * HDIM + t] = c;
  out_ctx[b * HDIM + t] = c;
}

__global__ __launch_bounds__(256) void k_rnn(const float* __restrict__ xt,
                                             const float* __restrict__ ctx,
                                             const float* __restrict__ hp,
                                             const float* __restrict__ Wih,
                                             const float* __restrict__ Wihb,
                                             const float* __restrict__ Whh,
                                             const float* __restrict__ Whhb,
                                             float* __restrict__ hout) {
  int b = blockIdx.x, oh = blockIdx.y;
  int o = oh * 256 + threadIdx.x;
  __shared__ float xs[EDIM], cs[HDIM], hs[HDIM];
  xs[threadIdx.x] = xt[b * EDIM + threadIdx.x];
  xs[threadIdx.x + 256] = xt[b * EDIM + threadIdx.x + 256];
  cs[threadIdx.x] = ctx[b * HDIM + threadIdx.x];
  cs[threadIdx.x + 256] = ctx[b * HDIM + threadIdx.x + 256];
  hs[threadIdx.x] = hp[b * HDIM + threadIdx.x];
  hs[threadIdx.x + 256] = hp[b * HDIM + threadIdx.x + 256];
  __syncthreads();
  const float4* wi = (const float4*)(Wih + (size_t)o * (EDIM + HDIM));
  float acc = Wihb[o] + Whhb[o];
#pragma unroll 8
  for (int i = 0; i < EDIM / 4; ++i) {
    float4 v = wi[i];
    acc += v.x * xs[i * 4] + v.y * xs[i * 4 + 1] + v.z * xs[i * 4 + 2] + v.w * xs[i * 4 + 3];
  }
  const float4* wi2 = wi + EDIM / 4;
#pragma unroll 8
  for (int i = 0; i < HDIM / 4; ++i) {
    float4 v = wi2[i];
    acc += v.x * cs[i * 4] + v.y * cs[i * 4 + 1] + v.z * cs[i * 4 + 2] + v.w * cs[i * 4 + 3];
  }
  const float4* wh = (const float4*)(Whh + (size_t)o * HDIM);
#pragma unroll 8
  for (int i = 0; i < HDIM / 4; ++i) {
    float4 v = wh[i];
    acc += v.x * hs[i * 4] + v.y * hs[i * 4 + 1] + v.z * hs[i * 4 + 2] + v.w * hs[i * 4 + 3];
  }
  hout[b * HDIM + o] = tanhf(acc);
}

extern "C" void kernel_launch(void* const* d_in, const int* in_sizes, int n_in,
                              void* d_out, int out_size, void* d_ws, size_t ws_size,
                              hipStream_t stream) {
  const float* x_t    = (const float*)d_in[0];
  const float* x_ref  = (const float*)d_in[1];
  const float* h_prev = (const float*)d_in[2];
  const float* Wa_w   = (const float*)d_in[3];
  const float* Wa_b   = (const float*)d_in[4];
  const float* Ua_w   = (const float*)d_in[5];
  const float* Ua_b   = (const float*)d_in[6];
  const float* Va_w   = (const float*)d_in[7];
  // d_in[8] = Va_b: softmax-invariant, skipped.
  const float* Wih_w  = (const float*)d_in[9];
  const float* Wih_b  = (const float*)d_in[10];
  const float* Whh_w  = (const float*)d_in[11];
  const float* Whh_b  = (const float*)d_in[12];

  char* ws = (char*)d_ws;
  unsigned short* ua_fr = (unsigned short*)ws;   // 512 KB fragment-layout Ua
  float* q     = (float*)(ws + 524288);          // 256 KB
  float* mArr  = (float*)(ws + 786432);          // 16 KB
  float* lArr  = (float*)(ws + 802816);          // 16 KB
  float* cpart = (float*)(ws + 819200);          // 8 MB
  float* ctx   = (float*)(ws + 9207808);         // 256 KB

  float* h_out   = (float*)d_out;
  float* ctx_out = h_out + BDIM * HDIM;

  k_cvt_b<<<dim3(128), dim3(256), 0, stream>>>(Ua_w, ua_fr);
  k_q<<<dim3(BDIM, 2), dim3(256), 0, stream>>>(h_prev, Wa_w, Wa_b, Ua_b, q);
  k_scores_ctx<<<dim3(NCHUNK, BDIM), dim3(512), 0, stream>>>(x_ref, ua_fr, q, Va_w, mArr, lArr, cpart);
  k_combine<<<dim3(BDIM), dim3(512), 0, stream>>>(mArr, lArr, cpart, ctx, ctx_out);
  k_rnn<<<dim3(BDIM, 2), dim3(256), 0, stream>>>(x_t, ctx, h_prev, Wih_w, Wih_b, Whh_w, Whh_b, h_out);
}

// Round 9
// 344.435 us; speedup vs baseline: 1.1449x; 1.1449x over previous
//
#include <hip/hip_runtime.h>
#include <hip/hip_bf16.h>
#include <math.h>

// Bahdanau attention + reservoir RNN cell.
//  K0: Ua_w f32 -> bf16 in MFMA B-fragment layout (L2-resident, read direct)
//  K1: q = h_prev@Wa^T + Wa_b + Ua_b
//  K2: per (b, 64-row chunk): 512 thr / 8 waves, acc 4x4/wave (64 AGPR).
//      A staged as RAW F32 via global_load_lds into 2x32KB LDS dbuf (no
//      staging VGPRs, no spill) with source-side XOR swizzle (rule #21:
//      linear LDS dest, pre-swizzled global src, XOR'd reads). bf16 cvt
//      happens per-cluster via packed __float22bfloat162_rn. (512,4):
//      2 blocks/CU resident -> cross-block overlap of staging/L2/MFMA.
//      B: fragment-layout from L2, per-cluster loads (16 waves/CU hide L2).
//      Epilogue: tanh(q+k)·Va -> partial softmax; context re-read from
//      global (L2-warm).
//  K3: exact combine of 32 partials -> context
//  K4: RNN cell (grid split over o for full-chip coverage)

typedef __attribute__((ext_vector_type(8))) short short8;
typedef __attribute__((ext_vector_type(8))) unsigned short ushort8;
typedef __attribute__((ext_vector_type(4))) float f32x4;

typedef __attribute__((address_space(1))) const unsigned int glob_uint;
typedef __attribute__((address_space(3))) unsigned int lds_uint;

#define S_LEN 2048
#define BDIM 128
#define HDIM 512
#define EDIM 512
#define BM 64
#define BK 128
#define NK (HDIM / BK)       // 4
#define NCHUNK (S_LEN / BM)  // 32

__device__ __forceinline__ unsigned short f2bf(float f) {
  unsigned int u = __float_as_uint(f);
  u += 0x7fffu + ((u >> 16) & 1u);  // RNE
  return (unsigned short)(u >> 16);
}

__device__ __forceinline__ float fast_tanh(float x) {
  float e = __expf(2.0f * x);
  return 1.0f - 2.0f / (e + 1.0f);
}

// Ua[512][512] f32 -> bf16 fragment layout:
// tile (ct,kt): col = ct*16 + (l&15), k = kt*32 + (l>>4)*8 + e
// at dst[((ct*16+kt)*64 + l)*8 + e]
__global__ __launch_bounds__(256) void k_cvt_b(const float* __restrict__ src,
                                               unsigned short* __restrict__ dst) {
  int tid = blockIdx.x * 256 + threadIdx.x;  // 0..32767
  int ct = tid >> 10;
  int kt = (tid >> 6) & 15;
  int l = tid & 63;
  int col = ct * 16 + (l & 15);
  int k = kt * 32 + (l >> 4) * 8;
  const float4* s = (const float4*)(src + (size_t)col * HDIM + k);
  float4 v0 = s[0], v1 = s[1];
  ushort8 p;
  p[0] = f2bf(v0.x); p[1] = f2bf(v0.y); p[2] = f2bf(v0.z); p[3] = f2bf(v0.w);
  p[4] = f2bf(v1.x); p[5] = f2bf(v1.y); p[6] = f2bf(v1.z); p[7] = f2bf(v1.w);
  *(ushort8*)(dst + (size_t)tid * 8) = p;
}

__global__ __launch_bounds__(256) void k_q(const float* __restrict__ hp,
                                           const float* __restrict__ Wa,
                                           const float* __restrict__ Wab,
                                           const float* __restrict__ Uab,
                                           float* __restrict__ q) {
  int b = blockIdx.x, oh = blockIdx.y;
  int o = oh * 256 + threadIdx.x;
  __shared__ float hs[HDIM];
  hs[threadIdx.x] = hp[b * HDIM + threadIdx.x];
  hs[threadIdx.x + 256] = hp[b * HDIM + threadIdx.x + 256];
  __syncthreads();
  const float4* wr = (const float4*)(Wa + (size_t)o * HDIM);
  float acc = 0.f;
#pragma unroll 8
  for (int i = 0; i < HDIM / 4; ++i) {
    float4 v = wr[i];
    acc += v.x * hs[i * 4 + 0] + v.y * hs[i * 4 + 1] + v.z * hs[i * 4 + 2] + v.w * hs[i * 4 + 3];
  }
  q[b * HDIM + o] = acc + Wab[o] + Uab[o];
}

__global__ __launch_bounds__(512, 4) void k_scores_ctx(
    const float* __restrict__ xref, const unsigned short* __restrict__ uab,
    const float* __restrict__ q, const float* __restrict__ va,
    float* __restrict__ mArr, float* __restrict__ lArr, float* __restrict__ cpart) {
  int chunk = blockIdx.x;
  int b = blockIdx.y;
  int tid = threadIdx.x;
  int l = tid & 63;
  int w = tid >> 6;   // 0..7, wave owns 64 output cols

  // A tile kc-slice as raw f32, XOR-swizzled within each 512-B row:
  // LDS byte (row*512 + z) holds x[row][kc*128 + (z ^ ((row&7)<<4))/4]
  __shared__ __align__(16) float Af[2][BM * BK];  // 2 x 32 KB
  __shared__ float sc[BM];
  __shared__ float pl[BM];

  f32x4 acc[4][4];
#pragma unroll
  for (int m = 0; m < 4; ++m)
#pragma unroll
    for (int n = 0; n < 4; ++n) acc[m][n] = f32x4{0.f, 0.f, 0.f, 0.f};

  const float* xb = xref + ((size_t)b * S_LEN + (size_t)chunk * BM) * HDIM;

  // staging source offsets (inverse swizzle): issue i of wave w covers LDS
  // bytes s = (w*4+i)*1024 + l*16; row = s>>9; kbyte = (s&511) ^ ((row&7)<<4)
  int srcoff[4];
#pragma unroll
  for (int i = 0; i < 4; ++i) {
    int s = (w * 4 + i) * 1024 + l * 16;
    int row = s >> 9;
    int kb = (s & 511) ^ ((row & 7) << 4);
    srcoff[i] = row * HDIM + (kb >> 2);
  }

  // per-lane A-frag read bases: row = m*16+(l&15); lanebase covers
  // (l>>4)*32 bytes XOR'd by ((l&7)<<4); +kk*128 immediate per cluster
  int lanebase = (((l >> 4) * 32) ^ ((l & 7) << 4));
  int vb0[4];
#pragma unroll
  for (int m = 0; m < 4; ++m) vb0[m] = (m * 16 + (l & 15)) * 512 + lanebase;

#define STAGE(buf, kc)                                                        \
  {                                                                           \
    _Pragma("unroll")                                                         \
    for (int i = 0; i < 4; ++i) {                                             \
      const float* gp = xb + (kc) * BK + srcoff[i];                           \
      float* lp = &Af[buf][(w * 4 + i) * 256];                                \
      __builtin_amdgcn_global_load_lds((glob_uint*)gp, (lds_uint*)lp, 16, 0, 0); \
    }                                                                         \
  }

#define CLUSTER(buf, kc, kk)                                                  \
  {                                                                           \
    short8 afr[4], bfr[4];                                                    \
    _Pragma("unroll")                                                         \
    for (int n = 0; n < 4; ++n) {                                             \
      int ct = w * 4 + n, kt = (kc) * 4 + (kk);                               \
      bfr[n] = *(const short8*)(uab + (((size_t)(ct * 16 + kt) * 64 + l) * 8)); \
    }                                                                         \
    const char* base_ = (const char*)&Af[buf][0];                             \
    _Pragma("unroll")                                                         \
    for (int m = 0; m < 4; ++m) {                                             \
      f32x4 u0 = *(const f32x4*)(base_ + vb0[m] + (kk) * 128);                \
      f32x4 u1 = *(const f32x4*)(base_ + (vb0[m] ^ 16) + (kk) * 128);         \
      union { __hip_bfloat162 h[4]; short8 s; } pk_;                          \
      pk_.h[0] = __float22bfloat162_rn(make_float2(u0[0], u0[1]));            \
      pk_.h[1] = __float22bfloat162_rn(make_float2(u0[2], u0[3]));            \
      pk_.h[2] = __float22bfloat162_rn(make_float2(u1[0], u1[1]));            \
      pk_.h[3] = __float22bfloat162_rn(make_float2(u1[2], u1[3]));            \
      afr[m] = pk_.s;                                                         \
    }                                                                         \
    __builtin_amdgcn_s_setprio(1);                                            \
    _Pragma("unroll")                                                         \
    for (int m = 0; m < 4; ++m)                                               \
      _Pragma("unroll")                                                       \
      for (int n = 0; n < 4; ++n)                                             \
        acc[m][n] = __builtin_amdgcn_mfma_f32_16x16x32_bf16(afr[m], bfr[n],   \
                                                            acc[m][n], 0, 0, 0); \
    __builtin_amdgcn_s_setprio(0);                                            \
  }

#define COMPUTEKC(buf, kc)  \
  CLUSTER(buf, kc, 0) CLUSTER(buf, kc, 1) CLUSTER(buf, kc, 2) CLUSTER(buf, kc, 3)

  STAGE(0, 0);
  if (tid < BM) sc[tid] = 0.f;
  __syncthreads();  // drains stage(0,0)

  STAGE(1, 1);
  COMPUTEKC(0, 0);
  __syncthreads();

  STAGE(0, 2);
  COMPUTEKC(1, 1);
  __syncthreads();

  STAGE(1, 3);
  COMPUTEKC(0, 2);
  __syncthreads();

  // hoist q/Va loads under the last compute phase
  int c = l & 15, g4 = l >> 4;
  float qf[4], vf[4];
#pragma unroll
  for (int n = 0; n < 4; ++n) {
    int o = w * 64 + n * 16 + c;
    qf[n] = q[b * HDIM + o];
    vf[n] = va[o];
  }
  COMPUTEKC(1, 3);

  // scores[row] = sum_o tanh(acc + q[o]) * Va[o]
#pragma unroll
  for (int m = 0; m < 4; ++m) {
#pragma unroll
    for (int r = 0; r < 4; ++r) {
      float sum = 0.f;
#pragma unroll
      for (int n = 0; n < 4; ++n) sum += fast_tanh(acc[m][n][r] + qf[n]) * vf[n];
      sum += __shfl_xor(sum, 1);
      sum += __shfl_xor(sum, 2);
      sum += __shfl_xor(sum, 4);
      sum += __shfl_xor(sum, 8);
      if (c == 0) atomicAdd(&sc[m * 16 + g4 * 4 + r], sum);
    }
  }
  __syncthreads();

  // partial softmax over the 64 local rows
  float M = sc[l];
#pragma unroll
  for (int off = 32; off >= 1; off >>= 1) M = fmaxf(M, __shfl_xor(M, off));
  float p = __expf(sc[l] - M);
  float lsum = p;
#pragma unroll
  for (int off = 32; off >= 1; off >>= 1) lsum += __shfl_xor(lsum, off);
  if (tid < BM) pl[tid] = p;
  if (tid == 0) {
    mArr[b * NCHUNK + chunk] = M;
    lArr[b * NCHUNK + chunk] = lsum;
  }
  __syncthreads();

  // partial context: re-read the f32 tile from global (L2-warm; coalesced)
  {
    float cacc = 0.f;
#pragma unroll 8
    for (int r = 0; r < BM; ++r) cacc += pl[r] * xb[(size_t)r * HDIM + tid];
    cpart[((size_t)b * NCHUNK + chunk) * HDIM + tid] = cacc;
  }
#undef STAGE
#undef CLUSTER
#undef COMPUTEKC
}

__global__ __launch_bounds__(512) void k_combine(const float* __restrict__ mArr,
                                                 const float* __restrict__ lArr,
                                                 const float* __restrict__ cpart,
                                                 float* __restrict__ ctx,
                                                 float* __restrict__ out_ctx) {
  int b = blockIdx.x, t = threadIdx.x;
  __shared__ float wf[NCHUNK];
  __shared__ float dinv;
  if (t == 0) {
    float M = mArr[b * NCHUNK];
    for (int i = 1; i < NCHUNK; ++i) M = fmaxf(M, mArr[b * NCHUNK + i]);
    float den = 0.f;
    for (int i = 0; i < NCHUNK; ++i) {
      float f = __expf(mArr[b * NCHUNK + i] - M);
      wf[i] = f;
      den += f * lArr[b * NCHUNK + i];
    }
    dinv = 1.0f / den;
  }
  __syncthreads();
  float s = 0.f;
#pragma unroll
  for (int i = 0; i < NCHUNK; ++i) s += wf[i] * cpart[((size_t)b * NCHUNK + i) * HDIM + t];
  float c = s * dinv;
  ctx[b * HDIM + t] = c;
  out_ctx[b * HDIM + t] = c;
}

__global__ __launch_bounds__(256) void k_rnn(const float* __restrict__ xt,
                                             const float* __restrict__ ctx,
                                             const float* __restrict__ hp,
                                             const float* __restrict__ Wih,
                                             const float* __restrict__ Wihb,
                                             const float* __restrict__ Whh,
                                             const float* __restrict__ Whhb,
                                             float* __restrict__ hout) {
  int b = blockIdx.x, oh = blockIdx.y;
  int o = oh * 256 + threadIdx.x;
  __shared__ float xs[EDIM], cs[HDIM], hs[HDIM];
  xs[threadIdx.x] = xt[b * EDIM + threadIdx.x];
  xs[threadIdx.x + 256] = xt[b * EDIM + threadIdx.x + 256];
  cs[threadIdx.x] = ctx[b * HDIM + threadIdx.x];
  cs[threadIdx.x + 256] = ctx[b * HDIM + threadIdx.x + 256];
  hs[threadIdx.x] = hp[b * HDIM + threadIdx.x];
  hs[threadIdx.x + 256] = hp[b * HDIM + threadIdx.x + 256];
  __syncthreads();
  const float4* wi = (const float4*)(Wih + (size_t)o * (EDIM + HDIM));
  float acc = Wihb[o] + Whhb[o];
#pragma unroll 8
  for (int i = 0; i < EDIM / 4; ++i) {
    float4 v = wi[i];
    acc += v.x * xs[i * 4] + v.y * xs[i * 4 + 1] + v.z * xs[i * 4 + 2] + v.w * xs[i * 4 + 3];
  }
  const float4* wi2 = wi + EDIM / 4;
#pragma unroll 8
  for (int i = 0; i < HDIM / 4; ++i) {
    float4 v = wi2[i];
    acc += v.x * cs[i * 4] + v.y * cs[i * 4 + 1] + v.z * cs[i * 4 + 2] + v.w * cs[i * 4 + 3];
  }
  const float4* wh = (const float4*)(Whh + (size_t)o * HDIM);
#pragma unroll 8
  for (int i = 0; i < HDIM / 4; ++i) {
    float4 v = wh[i];
    acc += v.x * hs[i * 4] + v.y * hs[i * 4 + 1] + v.z * hs[i * 4 + 2] + v.w * hs[i * 4 + 3];
  }
  hout[b * HDIM + o] = tanhf(acc);
}

extern "C" void kernel_launch(void* const* d_in, const int* in_sizes, int n_in,
                              void* d_out, int out_size, void* d_ws, size_t ws_size,
                              hipStream_t stream) {
  const float* x_t    = (const float*)d_in[0];
  const float* x_ref  = (const float*)d_in[1];
  const float* h_prev = (const float*)d_in[2];
  const float* Wa_w   = (const float*)d_in[3];
  const float* Wa_b   = (const float*)d_in[4];
  const float* Ua_w   = (const float*)d_in[5];
  const float* Ua_b   = (const float*)d_in[6];
  const float* Va_w   = (const float*)d_in[7];
  // d_in[8] = Va_b: softmax-invariant, skipped.
  const float* Wih_w  = (const float*)d_in[9];
  const float* Wih_b  = (const float*)d_in[10];
  const float* Whh_w  = (const float*)d_in[11];
  const float* Whh_b  = (const float*)d_in[12];

  char* ws = (char*)d_ws;
  unsigned short* ua_fr = (unsigned short*)ws;   // 512 KB fragment-layout Ua
  float* q     = (float*)(ws + 524288);          // 256 KB
  float* mArr  = (float*)(ws + 786432);          // 16 KB
  float* lArr  = (float*)(ws + 802816);          // 16 KB
  float* cpart = (float*)(ws + 819200);          // 8 MB
  float* ctx   = (float*)(ws + 9207808);         // 256 KB

  float* h_out   = (float*)d_out;
  float* ctx_out = h_out + BDIM * HDIM;

  k_cvt_b<<<dim3(128), dim3(256), 0, stream>>>(Ua_w, ua_fr);
  k_q<<<dim3(BDIM, 2), dim3(256), 0, stream>>>(h_prev, Wa_w, Wa_b, Ua_b, q);
  k_scores_ctx<<<dim3(NCHUNK, BDIM), dim3(512), 0, stream>>>(x_ref, ua_fr, q, Va_w, mArr, lArr, cpart);
  k_combine<<<dim3(BDIM), dim3(512), 0, stream>>>(mArr, lArr, cpart, ctx, ctx_out);
  k_rnn<<<dim3(BDIM, 2), dim3(256), 0, stream>>>(x_t, ctx, h_prev, Wih_w, Wih_b, Whh_w, Whh_b, h_out);
}